// Round 1
// baseline (81.188 us; speedup 1.0000x reference)
//
#include <hip/hip_runtime.h>

#define H 32
#define C 64
#define K 15
#define SIGMA 0.3f

__global__ __launch_bounds__(256) void kpconv_kernel(
    const float* __restrict__ q_pts,
    const float* __restrict__ s_pts,
    const float* __restrict__ s_feats,
    const int*   __restrict__ inds,
    const float* __restrict__ weights,
    const float* __restrict__ kpts,
    float*       __restrict__ out,
    int N)
{
    __shared__ float lds_w[K * C];     // 3840 B
    __shared__ float lds_kp[K * 3];    // 180 B

    const int tid = threadIdx.x;
    for (int i = tid; i < K * C; i += 256) lds_w[i] = weights[i];
    if (tid < K * 3) lds_kp[tid] = kpts[tid];
    __syncthreads();

    const int wave = tid >> 6;          // 4 waves / block
    const int lane = tid & 63;
    const int m = blockIdx.x * 4 + wave;
    if (m >= N) return;

    // ---- Phase A: lanes 0..31 each handle one neighbor ----
    float infl  = 0.0f;
    int   kbest = 0;
    int   idx   = 0;
    if (lane < H) {
        idx = inds[m * H + lane];
        if (idx >= 0 && idx < N) {
            const float qx = q_pts[m * 3 + 0];
            const float qy = q_pts[m * 3 + 1];
            const float qz = q_pts[m * 3 + 2];
            const float nx = s_pts[idx * 3 + 0] - qx;
            const float ny = s_pts[idx * 3 + 1] - qy;
            const float nz = s_pts[idx * 3 + 2] - qz;
            float best = 1e30f;
            #pragma unroll
            for (int k = 0; k < K; ++k) {
                const float dx = nx - lds_kp[k * 3 + 0];
                const float dy = ny - lds_kp[k * 3 + 1];
                const float dz = nz - lds_kp[k * 3 + 2];
                const float d2 = dx * dx + dy * dy + dz * dz;
                if (d2 < best) { best = d2; kbest = k; }
            }
            infl = 1.0f - sqrtf(best) / SIGMA;
            if (infl < 0.0f) infl = 0.0f;
        } else {
            idx  = 0;     // shadow: zero influence
            infl = 0.0f;
        }
    }

    // ---- Phase B: lane = channel; broadcast per-neighbor scalars ----
    float acc = 0.0f;
    #pragma unroll 4
    for (int h = 0; h < H; ++h) {
        const float inf_h = __shfl(infl, h);
        if (inf_h > 0.0f) {                       // wave-uniform branch
            const int idx_h = __shfl(idx, h);
            const int k_h   = __shfl(kbest, h);
            acc += s_feats[idx_h * C + lane] * lds_w[k_h * C + lane] * inf_h;
        }
    }
    out[m * C + lane] = acc;
}

extern "C" void kernel_launch(void* const* d_in, const int* in_sizes, int n_in,
                              void* d_out, int out_size, void* d_ws, size_t ws_size,
                              hipStream_t stream) {
    const float* q_pts   = (const float*)d_in[0];
    const float* s_pts   = (const float*)d_in[1];
    const float* s_feats = (const float*)d_in[2];
    const int*   inds    = (const int*)d_in[3];
    const float* weights = (const float*)d_in[4];
    const float* kpts    = (const float*)d_in[5];
    float* out = (float*)d_out;

    const int N = in_sizes[0] / 3;               // q_pts is (N,3)
    const int blocks = (N + 3) / 4;              // 4 queries per 256-thread block
    kpconv_kernel<<<blocks, 256, 0, stream>>>(q_pts, s_pts, s_feats, inds,
                                              weights, kpts, out, N);
}

// Round 2
// 56.269 us; speedup vs baseline: 1.4429x; 1.4429x over previous
//
#include <hip/hip_runtime.h>

#define H 32
#define C 64
#define K 15
#define SIGMA 0.3f

__global__ __launch_bounds__(256) void kpconv_kernel(
    const float* __restrict__ q_pts,
    const float* __restrict__ s_pts,
    const float* __restrict__ s_feats,
    const int*   __restrict__ inds,
    const float* __restrict__ weights,
    const float* __restrict__ kpts,
    float*       __restrict__ out,
    int N)
{
    __shared__ float lds_w[K * C];     // 3840 B
    __shared__ float lds_kp[K * 3];    // 180 B

    const int tid = threadIdx.x;
    for (int i = tid; i < K * C; i += 256) lds_w[i] = weights[i];
    if (tid < K * 3) lds_kp[tid] = kpts[tid];
    __syncthreads();

    const int wave = tid >> 6;          // 4 waves / block
    const int lane = tid & 63;
    const int m = blockIdx.x * 4 + wave;
    if (m >= N) return;

    // ---- Phase A: lanes 0..31 each handle one neighbor ----
    float infl   = 0.0f;
    int   packed = 0;                   // idx | (kbest << 20)
    if (lane < H) {
        const int idx = inds[m * H + lane];
        if (idx >= 0 && idx < N) {
            const float qx = q_pts[m * 3 + 0];   // m wave-uniform -> scalar loads
            const float qy = q_pts[m * 3 + 1];
            const float qz = q_pts[m * 3 + 2];
            const float nx = s_pts[idx * 3 + 0] - qx;
            const float ny = s_pts[idx * 3 + 1] - qy;
            const float nz = s_pts[idx * 3 + 2] - qz;
            float best = 1e30f;
            int   kbest = 0;
            #pragma unroll
            for (int k = 0; k < K; ++k) {
                const float dx = nx - lds_kp[k * 3 + 0];
                const float dy = ny - lds_kp[k * 3 + 1];
                const float dz = nz - lds_kp[k * 3 + 2];
                const float d2 = dx * dx + dy * dy + dz * dz;
                if (d2 < best) { best = d2; kbest = k; }
            }
            infl = 1.0f - sqrtf(best) / SIGMA;
            if (infl < 0.0f) infl = 0.0f;
            packed = idx | (kbest << 20);
        }
    }

    // ---- Phase B: compact active neighbors, lane = channel ----
    unsigned long long mask = __ballot(infl > 0.0f);   // lanes >= H have infl==0
    float acc = 0.0f;

    while (mask) {
        const int h0 = __ffsll(mask) - 1;  mask &= mask - 1;
        const int   p0 = __shfl(packed, h0);
        const float f0 = __shfl(infl,  h0);
        if (mask) {
            const int h1 = __ffsll(mask) - 1;  mask &= mask - 1;
            const int   p1 = __shfl(packed, h1);
            const float f1 = __shfl(infl,  h1);
            // two independent gathers in flight
            const float a0 = s_feats[(p0 & 0xFFFFF) * C + lane];
            const float w0 = lds_w[(p0 >> 20) * C + lane];
            const float a1 = s_feats[(p1 & 0xFFFFF) * C + lane];
            const float w1 = lds_w[(p1 >> 20) * C + lane];
            acc += a0 * w0 * f0;
            acc += a1 * w1 * f1;
        } else {
            const float a0 = s_feats[(p0 & 0xFFFFF) * C + lane];
            const float w0 = lds_w[(p0 >> 20) * C + lane];
            acc += a0 * w0 * f0;
        }
    }
    out[m * C + lane] = acc;
}

extern "C" void kernel_launch(void* const* d_in, const int* in_sizes, int n_in,
                              void* d_out, int out_size, void* d_ws, size_t ws_size,
                              hipStream_t stream) {
    const float* q_pts   = (const float*)d_in[0];
    const float* s_pts   = (const float*)d_in[1];
    const float* s_feats = (const float*)d_in[2];
    const int*   inds    = (const int*)d_in[3];
    const float* weights = (const float*)d_in[4];
    const float* kpts    = (const float*)d_in[5];
    float* out = (float*)d_out;

    const int N = in_sizes[0] / 3;               // q_pts is (N,3)
    const int blocks = (N + 3) / 4;              // 4 queries per 256-thread block
    kpconv_kernel<<<blocks, 256, 0, stream>>>(q_pts, s_pts, s_feats, inds,
                                              weights, kpts, out, N);
}

// Round 3
// 48.777 us; speedup vs baseline: 1.6645x; 1.1536x over previous
//
#include <hip/hip_runtime.h>

#define H 32
#define C 64
#define K 15
#define SIGMA 0.3f

__global__ __launch_bounds__(256) void kpconv_kernel(
    const float* __restrict__ q_pts,
    const float* __restrict__ s_pts,
    const float* __restrict__ s_feats,
    const int*   __restrict__ inds,
    const float* __restrict__ weights,
    const float* __restrict__ kpts,
    float*       __restrict__ out,
    int N)
{
    __shared__ float lds_w[K * C];     // 3840 B
    __shared__ float lds_kp[K * 3];    // 180 B

    const int tid = threadIdx.x;
    for (int i = tid; i < K * C; i += 256) lds_w[i] = weights[i];
    if (tid < K * 3) lds_kp[tid] = kpts[tid];
    __syncthreads();

    const int wave = tid >> 6;          // 4 waves / block
    const int lane = tid & 63;
    const int half = lane >> 5;         // which query of the wave's pair
    const int hl   = lane & 31;         // neighbor slot within query
    const int mBase = blockIdx.x * 8 + wave * 2;   // 8 queries / block
    const int m = mBase + half;

    // ---- Phase A: all 64 lanes active (2 queries x 32 neighbors) ----
    float infl   = 0.0f;
    int   packed = 0;                   // idx | (kbest << 20)
    if (m < N) {
        const int idx = inds[m * H + hl];   // contiguous 256B per wave
        if (idx >= 0 && idx < N) {
            const float qx = q_pts[m * 3 + 0];
            const float qy = q_pts[m * 3 + 1];
            const float qz = q_pts[m * 3 + 2];
            const float nx = s_pts[idx * 3 + 0] - qx;
            const float ny = s_pts[idx * 3 + 1] - qy;
            const float nz = s_pts[idx * 3 + 2] - qz;
            float best = 1e30f;
            int   kbest = 0;
            #pragma unroll
            for (int k = 0; k < K; ++k) {
                const float dx = nx - lds_kp[k * 3 + 0];
                const float dy = ny - lds_kp[k * 3 + 1];
                const float dz = nz - lds_kp[k * 3 + 2];
                const float d2 = dx * dx + dy * dy + dz * dz;
                if (d2 < best) { best = d2; kbest = k; }
            }
            infl = 1.0f - sqrtf(best) / SIGMA;
            if (infl < 0.0f) infl = 0.0f;
            packed = idx | (kbest << 20);
        }
    }

    // ---- Phase B: two compacted masks, interleaved (2 gather chains) ----
    const unsigned long long ball = __ballot(infl > 0.0f);
    unsigned int maskA = (unsigned int)(ball & 0xFFFFFFFFull);
    unsigned int maskB = (unsigned int)(ball >> 32);

    float accA = 0.0f, accB = 0.0f;
    while (maskA | maskB) {
        if (maskA) {
            const int h = __ffs(maskA) - 1;  maskA &= maskA - 1;
            const int   p = __shfl(packed, h);          // lanes 0..31 hold query A
            const float f = __shfl(infl,  h);
            accA += s_feats[(p & 0xFFFFF) * C + lane] * lds_w[(p >> 20) * C + lane] * f;
        }
        if (maskB) {
            const int h = __ffs(maskB) - 1;  maskB &= maskB - 1;
            const int   p = __shfl(packed, h + 32);     // lanes 32..63 hold query B
            const float f = __shfl(infl,  h + 32);
            accB += s_feats[(p & 0xFFFFF) * C + lane] * lds_w[(p >> 20) * C + lane] * f;
        }
    }

    if (mBase < N)     out[mBase * C + lane]       = accA;  // 256B coalesced
    if (mBase + 1 < N) out[(mBase + 1) * C + lane] = accB;  // adjacent row
}

extern "C" void kernel_launch(void* const* d_in, const int* in_sizes, int n_in,
                              void* d_out, int out_size, void* d_ws, size_t ws_size,
                              hipStream_t stream) {
    const float* q_pts   = (const float*)d_in[0];
    const float* s_pts   = (const float*)d_in[1];
    const float* s_feats = (const float*)d_in[2];
    const int*   inds    = (const int*)d_in[3];
    const float* weights = (const float*)d_in[4];
    const float* kpts    = (const float*)d_in[5];
    float* out = (float*)d_out;

    const int N = in_sizes[0] / 3;               // q_pts is (N,3)
    const int blocks = (N + 7) / 8;              // 8 queries per 256-thread block
    kpconv_kernel<<<blocks, 256, 0, stream>>>(q_pts, s_pts, s_feats, inds,
                                              weights, kpts, out, N);
}

// Round 4
// 42.434 us; speedup vs baseline: 1.9133x; 1.1495x over previous
//
#include <hip/hip_runtime.h>

#define H 32
#define C 64
#define K 15
#define SIGMA 0.3f

__global__ __launch_bounds__(256) void kpconv_kernel(
    const float* __restrict__ q_pts,
    const float* __restrict__ s_pts,
    const float* __restrict__ s_feats,
    const int*   __restrict__ inds,
    const float* __restrict__ weights,
    const float* __restrict__ kpts,
    float*       __restrict__ out,
    int N)
{
    const int tid  = threadIdx.x;
    const int wave = tid >> 6;          // 4 waves / block, fully independent
    const int lane = tid & 63;
    const int half = lane >> 5;         // which query of the wave's pair
    const int hl   = lane & 31;         // neighbor slot within query
    const int mBase = blockIdx.x * 8 + wave * 2;   // 8 queries / block
    const int m = mBase + half;

    // Kernel points are wave-uniform: compile-time-constant indices off a
    // uniform pointer -> compiler emits s_load into SGPRs (45 scalars).
    float kp[K * 3];
    #pragma unroll
    for (int i = 0; i < K * 3; ++i) kp[i] = kpts[i];

    // ---- Phase A: all 64 lanes active (2 queries x 32 neighbors) ----
    float infl   = 0.0f;
    int   packed = 0;                   // idx | (kbest << 20)
    if (m < N) {
        const int idx = inds[m * H + hl];   // contiguous 256B per wave
        if (idx >= 0 && idx < N) {
            const float qx = q_pts[m * 3 + 0];
            const float qy = q_pts[m * 3 + 1];
            const float qz = q_pts[m * 3 + 2];
            const float nx = s_pts[idx * 3 + 0] - qx;
            const float ny = s_pts[idx * 3 + 1] - qy;
            const float nz = s_pts[idx * 3 + 2] - qz;
            float best = 1e30f;
            int   kbest = 0;
            #pragma unroll
            for (int k = 0; k < K; ++k) {
                const float dx = nx - kp[k * 3 + 0];
                const float dy = ny - kp[k * 3 + 1];
                const float dz = nz - kp[k * 3 + 2];
                const float d2 = dx * dx + dy * dy + dz * dz;
                if (d2 < best) { best = d2; kbest = k; }
            }
            infl = 1.0f - sqrtf(best) / SIGMA;
            if (infl < 0.0f) infl = 0.0f;
            packed = idx | (kbest << 20);
        }
    }

    // ---- Phase B: two compacted masks, interleaved (2 gather chains) ----
    const unsigned long long ball = __ballot(infl > 0.0f);
    unsigned int maskA = (unsigned int)(ball & 0xFFFFFFFFull);
    unsigned int maskB = (unsigned int)(ball >> 32);

    float accA = 0.0f, accB = 0.0f;
    while (maskA | maskB) {
        if (maskA) {
            const int h = __ffs(maskA) - 1;  maskA &= maskA - 1;
            const int   p = __shfl(packed, h);          // lanes 0..31: query A
            const float f = __shfl(infl,  h);
            // weights table is 3.8 KB -> permanently L1-resident
            accA += s_feats[(p & 0xFFFFF) * C + lane]
                  * weights[(p >> 20) * C + lane] * f;
        }
        if (maskB) {
            const int h = __ffs(maskB) - 1;  maskB &= maskB - 1;
            const int   p = __shfl(packed, h + 32);     // lanes 32..63: query B
            const float f = __shfl(infl,  h + 32);
            accB += s_feats[(p & 0xFFFFF) * C + lane]
                  * weights[(p >> 20) * C + lane] * f;
        }
    }

    if (mBase < N)     out[mBase * C + lane]       = accA;  // 256B coalesced
    if (mBase + 1 < N) out[(mBase + 1) * C + lane] = accB;  // adjacent row
}

extern "C" void kernel_launch(void* const* d_in, const int* in_sizes, int n_in,
                              void* d_out, int out_size, void* d_ws, size_t ws_size,
                              hipStream_t stream) {
    const float* q_pts   = (const float*)d_in[0];
    const float* s_pts   = (const float*)d_in[1];
    const float* s_feats = (const float*)d_in[2];
    const int*   inds    = (const int*)d_in[3];
    const float* weights = (const float*)d_in[4];
    const float* kpts    = (const float*)d_in[5];
    float* out = (float*)d_out;

    const int N = in_sizes[0] / 3;               // q_pts is (N,3)
    const int blocks = (N + 7) / 8;              // 8 queries per 256-thread block
    kpconv_kernel<<<blocks, 256, 0, stream>>>(q_pts, s_pts, s_feats, inds,
                                              weights, kpts, out, N);
}

// Round 5
// 35.861 us; speedup vs baseline: 2.2640x; 1.1833x over previous
//
#include <hip/hip_runtime.h>

#define H 32
#define C 64
#define K 15
#define SIGMA 0.3f
#define WAVES 4

__global__ __launch_bounds__(256) void kpconv_kernel(
    const float* __restrict__ q_pts,
    const float* __restrict__ s_pts,
    const float* __restrict__ s_feats,
    const int*   __restrict__ inds,
    const float* __restrict__ weights,
    const float* __restrict__ kpts,
    float*       __restrict__ out,
    int N)
{
    __shared__ float2 list[WAVES][2][32];   // 2 KB, wave-private slices

    const int tid  = threadIdx.x;
    const int wave = tid >> 6;
    const int lane = tid & 63;
    const int half = lane >> 5;         // which query of the wave's pair
    const int hl   = lane & 31;         // neighbor slot / channel-pair slot
    const int mBase = blockIdx.x * (WAVES * 2) + wave * 2;
    const int m = mBase + half;

    // wave-uniform kernel points -> SGPRs via s_load
    float kp[K * 3];
    #pragma unroll
    for (int i = 0; i < K * 3; ++i) kp[i] = kpts[i];

    // ---- Phase A: all 64 lanes active (2 queries x 32 neighbors) ----
    float infl   = 0.0f;
    int   packed = 0;                   // idx | (kbest << 20)
    if (m < N) {
        const int idx = inds[m * H + hl];   // 2x128B contiguous per wave
        if (idx >= 0 && idx < N) {
            const float qx = q_pts[m * 3 + 0];
            const float qy = q_pts[m * 3 + 1];
            const float qz = q_pts[m * 3 + 2];
            const float nx = s_pts[idx * 3 + 0] - qx;
            const float ny = s_pts[idx * 3 + 1] - qy;
            const float nz = s_pts[idx * 3 + 2] - qz;
            float best = 1e30f;
            int   kbest = 0;
            #pragma unroll
            for (int k = 0; k < K; ++k) {
                const float dx = nx - kp[k * 3 + 0];
                const float dy = ny - kp[k * 3 + 1];
                const float dz = nz - kp[k * 3 + 2];
                const float d2 = dx * dx + dy * dy + dz * dz;
                if (d2 < best) { best = d2; kbest = k; }
            }
            infl = 1.0f - sqrtf(best) / SIGMA;
            if (infl < 0.0f) infl = 0.0f;
            packed = idx | (kbest << 20);
        }
    }

    // ---- Compact actives into wave-private LDS lists (rank = popc below) ----
    const unsigned long long ball = __ballot(infl > 0.0f);
    const unsigned int maskH = half ? (unsigned int)(ball >> 32)
                                    : (unsigned int)(ball & 0xFFFFFFFFu);
    const int rank = __popc(maskH & ((1u << hl) - 1u));
    if (infl > 0.0f)
        list[wave][half][rank] = make_float2(__int_as_float(packed), infl);
    const int cnt = __popc(maskH);
    // same-wave LDS RAW: DS pipe is in-order per wave; no barrier needed.

    // ---- Phase B: half-wave per query, float2 channels, 2 pops/iter ----
    float2 acc = make_float2(0.0f, 0.0f);
    const float2* wrows = (const float2*)weights;
    for (int i = 0; i < cnt; i += 2) {
        const float4 pf = *(const float4*)&list[wave][half][i];  // 16B aligned
        const int   p0   = __float_as_int(pf.x);
        const float f0   = pf.y;
        const bool  has1 = (i + 1) < cnt;
        const int   p1   = has1 ? __float_as_int(pf.z) : 0;   // row 0: cached
        const float f1   = has1 ? pf.w : 0.0f;
        const float2 a0 = ((const float2*)(s_feats + (size_t)(p0 & 0xFFFFF) * C))[hl];
        const float2 w0 = wrows[(p0 >> 20) * (C / 2) + hl];
        const float2 a1 = ((const float2*)(s_feats + (size_t)(p1 & 0xFFFFF) * C))[hl];
        const float2 w1 = wrows[(p1 >> 20) * (C / 2) + hl];
        acc.x += a0.x * w0.x * f0;
        acc.y += a0.y * w0.y * f0;
        acc.x += a1.x * w1.x * f1;
        acc.y += a1.y * w1.y * f1;
    }

    if (m < N)
        *(float2*)(out + (size_t)m * C + hl * 2) = acc;   // 256B per half-wave
}

extern "C" void kernel_launch(void* const* d_in, const int* in_sizes, int n_in,
                              void* d_out, int out_size, void* d_ws, size_t ws_size,
                              hipStream_t stream) {
    const float* q_pts   = (const float*)d_in[0];
    const float* s_pts   = (const float*)d_in[1];
    const float* s_feats = (const float*)d_in[2];
    const int*   inds    = (const int*)d_in[3];
    const float* weights = (const float*)d_in[4];
    const float* kpts    = (const float*)d_in[5];
    float* out = (float*)d_out;

    const int N = in_sizes[0] / 3;               // q_pts is (N,3)
    const int blocks = (N + WAVES * 2 - 1) / (WAVES * 2);   // 8 queries / block
    kpconv_kernel<<<blocks, 256, 0, stream>>>(q_pts, s_pts, s_feats, inds,
                                              weights, kpts, out, N);
}